// Round 1
// baseline (738.536 us; speedup 1.0000x reference)
//
#include <hip/hip_runtime.h>

#define N_NODES 100000
#define N_EDGES 1600000
#define D_IN 128
#define D_HID 64

// ---------------- degree / normalization ----------------

__global__ void k_init_deg(float* __restrict__ deg, int n) {
    int i = blockIdx.x * blockDim.x + threadIdx.x;
    if (i < n) deg[i] = 1.0f;  // self-loop counts 1
}

__global__ void k_deg(const int* __restrict__ dst, float* __restrict__ deg, int E) {
    int e = blockIdx.x * blockDim.x + threadIdx.x;
    if (e < E) atomicAdd(&deg[dst[e]], 1.0f);
}

__global__ void k_rsqrt(float* __restrict__ deg, int n) {
    int i = blockIdx.x * blockDim.x + threadIdx.x;
    if (i < n) deg[i] = rsqrtf(deg[i]);  // deg >= 1 always (self-loop)
}

// ---------------- layer 1: h1 = x @ W1 ----------------
// One wave per node row: lane f computes h1[node][f] = sum_k x[node][k]*W1[k][f].
// Block = 256 threads = 4 nodes. x rows staged in LDS; W1 reads coalesced (L1-hot, 32KB).
__global__ __launch_bounds__(256) void k_gemm1(const float* __restrict__ x,
                                               const float* __restrict__ W1,
                                               float* __restrict__ h1, int n) {
    __shared__ float xs[4 * D_IN];
    int node0 = blockIdx.x * 4;
    int tid = threadIdx.x;
    // 4 rows * 128 floats = 512 floats = 256 float2 loads
    const float2* x2 = (const float2*)(x + (size_t)node0 * D_IN);
    ((float2*)xs)[tid] = x2[tid];
    __syncthreads();
    int r = tid >> 6;       // 0..3 node within block
    int f = tid & 63;       // output feature
    int node = node0 + r;
    if (node < n) {
        const float* xr = xs + r * D_IN;
        float acc = 0.0f;
#pragma unroll 8
        for (int k = 0; k < D_IN; ++k)
            acc = fmaf(xr[k], W1[k * D_HID + f], acc);
        h1[(size_t)node * D_HID + f] = acc;
    }
}

// ---------------- aggregation 1 ----------------
// self-loop contribution: agg1[i] = h1[i] * dis[i]^2
__global__ void k_selfloop1(const float* __restrict__ h1, const float* __restrict__ dis,
                            float* __restrict__ agg1, int n) {
    int idx = blockIdx.x * blockDim.x + threadIdx.x;
    if (idx < n * D_HID) {
        int i = idx >> 6;
        float d = dis[i];
        agg1[idx] = h1[idx] * d * d;
    }
}

// edge scatter: one wave (64 lanes) per edge, lane = feature
__global__ __launch_bounds__(256) void k_scatter1(const int* __restrict__ src,
                                                  const int* __restrict__ dst,
                                                  const float* __restrict__ dis,
                                                  const float* __restrict__ h1,
                                                  float* __restrict__ agg1, int E) {
    long long gid = (long long)blockIdx.x * blockDim.x + threadIdx.x;
    int e = (int)(gid >> 6);
    int f = (int)(gid & 63);
    if (e < E) {
        int s = src[e];        // same address across wave -> broadcast
        int d = dst[e];
        float nrm = dis[s] * dis[d];
        atomicAdd(&agg1[(size_t)d * D_HID + f], h1[(size_t)s * D_HID + f] * nrm);
    }
}

// ---------------- layer 2: fused bias+relu+dot(W2), plus self-loop init of yagg ----------------
// One wave per node. lane f: relu(agg1[i][f]+b1[f]) * W2[f], wave-reduce sum.
__global__ __launch_bounds__(256) void k_layer2(const float* __restrict__ agg1,
                                                const float* __restrict__ b1,
                                                const float* __restrict__ W2,
                                                const float* __restrict__ dis,
                                                float* __restrict__ z,
                                                float* __restrict__ yagg, int n) {
    int gid = blockIdx.x * blockDim.x + threadIdx.x;
    int i = gid >> 6;
    int f = gid & 63;
    if (i < n) {
        float v = agg1[(size_t)i * D_HID + f] + b1[f];
        v = fmaxf(v, 0.0f) * W2[f];
        // full-wave (64-lane) butterfly reduce
        for (int off = 32; off > 0; off >>= 1)
            v += __shfl_down(v, off);
        if (f == 0) {
            z[i] = v;
            float d = dis[i];
            yagg[i] = v * d * d;   // self-loop contribution
        }
    }
}

// edge scatter for layer 2: one thread per edge
__global__ void k_scatter2(const int* __restrict__ src, const int* __restrict__ dst,
                           const float* __restrict__ dis, const float* __restrict__ z,
                           float* __restrict__ yagg, int E) {
    int e = blockIdx.x * blockDim.x + threadIdx.x;
    if (e < E) {
        int s = src[e], d = dst[e];
        atomicAdd(&yagg[d], z[s] * dis[s] * dis[d]);
    }
}

// ---------------- output: [N,1] -> padded [N,128] ----------------
__global__ void k_out(const float* __restrict__ yagg, const float* __restrict__ b2,
                      float* __restrict__ out, int n) {
    int gid = blockIdx.x * blockDim.x + threadIdx.x;  // n*32 threads, each writes float4
    int i = gid >> 5;
    int t = gid & 31;
    if (i < n) {
        float4 v = make_float4(0.f, 0.f, 0.f, 0.f);
        if (t == 0) v.x = yagg[i] + b2[0];
        ((float4*)out)[(size_t)i * 32 + t] = v;
    }
}

extern "C" void kernel_launch(void* const* d_in, const int* in_sizes, int n_in,
                              void* d_out, int out_size, void* d_ws, size_t ws_size,
                              hipStream_t stream) {
    const float* x  = (const float*)d_in[0];
    const int*   ei = (const int*)d_in[1];   // [2, E] int32
    const float* W1 = (const float*)d_in[2];
    const float* b1 = (const float*)d_in[3];
    const float* W2 = (const float*)d_in[4];
    const float* b2 = (const float*)d_in[5];
    float* out = (float*)d_out;
    float* ws  = (float*)d_ws;

    const int n = N_NODES;
    const int E = N_EDGES;
    const int* src = ei;
    const int* dst = ei + E;

    // workspace layout (floats): dis[n] | h1[n*64] | agg1[n*64] | z[n] | yagg[n]  = 131n ~ 52.4MB
    float* dis  = ws;
    float* h1   = ws + n;
    float* agg1 = h1 + (size_t)n * D_HID;
    float* z    = agg1 + (size_t)n * D_HID;
    float* yagg = z + n;

    k_init_deg<<<(n + 255) / 256, 256, 0, stream>>>(dis, n);
    k_deg<<<(E + 255) / 256, 256, 0, stream>>>(dst, dis, E);
    k_rsqrt<<<(n + 255) / 256, 256, 0, stream>>>(dis, n);

    k_gemm1<<<n / 4, 256, 0, stream>>>(x, W1, h1, n);

    k_selfloop1<<<(n * D_HID + 255) / 256, 256, 0, stream>>>(h1, dis, agg1, n);
    k_scatter1<<<E / 4, 256, 0, stream>>>(src, dst, dis, h1, agg1, E);

    k_layer2<<<(n * D_HID + 255) / 256, 256, 0, stream>>>(agg1, b1, W2, dis, z, yagg, n);
    k_scatter2<<<(E + 255) / 256, 256, 0, stream>>>(src, dst, dis, z, yagg, E);

    k_out<<<(n * 32 + 255) / 256, 256, 0, stream>>>(yagg, b2, out, n);
}

// Round 2
// 567.023 us; speedup vs baseline: 1.3025x; 1.3025x over previous
//
#include <hip/hip_runtime.h>

#define N_NODES 100000
#define N_EDGES 1600000
#define D_IN 128
#define D_HID 64

// ================= degree histogram / normalization =================

__global__ void k_zero_counts(int* __restrict__ counts, int n) {
    int i = blockIdx.x * blockDim.x + threadIdx.x;
    if (i < n) counts[i] = 0;
}

__global__ void k_count(const int* __restrict__ dst, int* __restrict__ counts, int E) {
    int e = blockIdx.x * blockDim.x + threadIdx.x;
    if (e < E) atomicAdd(&counts[dst[e]], 1);
}

// dis[i] = rsqrt(deg[i]) with deg = in-edges + 1 (self-loop)
__global__ void k_dis(const int* __restrict__ counts, float* __restrict__ dis, int n) {
    int i = blockIdx.x * blockDim.x + threadIdx.x;
    if (i < n) dis[i] = rsqrtf((float)counts[i] + 1.0f);
}

// ================= 2-level exclusive scan (CSR row starts) =================

__global__ __launch_bounds__(256) void k_scanA(const int* __restrict__ counts,
                                               int* __restrict__ excl,
                                               int* __restrict__ bsums, int n) {
    __shared__ int sh[256];
    int i = blockIdx.x * 256 + threadIdx.x;
    int v = (i < n) ? counts[i] : 0;
    sh[threadIdx.x] = v;
    __syncthreads();
    int acc = v;
    for (int off = 1; off < 256; off <<= 1) {
        int t = (threadIdx.x >= (unsigned)off) ? sh[threadIdx.x - off] : 0;
        __syncthreads();
        acc += t;
        sh[threadIdx.x] = acc;
        __syncthreads();
    }
    if (i < n) excl[i] = acc - v;            // exclusive within block
    if (threadIdx.x == 255) bsums[blockIdx.x] = acc;  // block total
}

__global__ void k_scanB(int* __restrict__ bsums, int nb) {
    if (blockIdx.x == 0 && threadIdx.x == 0) {
        int acc = 0;
        for (int b = 0; b < nb; ++b) { int t = bsums[b]; bsums[b] = acc; acc += t; }
    }
}

__global__ void k_scanC(const int* __restrict__ excl, const int* __restrict__ bsums,
                        int* __restrict__ row_start, int* __restrict__ cursor, int n) {
    int i = blockIdx.x * blockDim.x + threadIdx.x;
    if (i < n) {
        int v = excl[i] + bsums[blockIdx.x * 256 / 256 + (i >> 8) - (i >> 8) + (i >> 8)];
        // (simplify: block index of element i in scanA was i>>8)
        v = excl[i] + bsums[i >> 8];
        row_start[i] = v;
        cursor[i] = v;
    }
}

// ================= CSR fill (counting-sort scatter of src ids) =================

__global__ void k_fill(const int* __restrict__ src, const int* __restrict__ dst,
                       int* __restrict__ cursor, int* __restrict__ srcs_sorted, int E) {
    int e = blockIdx.x * blockDim.x + threadIdx.x;
    if (e < E) {
        int d = dst[e];
        int pos = atomicAdd(&cursor[d], 1);
        srcs_sorted[pos] = src[e];
    }
}

// ================= layer 1 GEMM: h1 = x @ W1 =================
// one wave per node row; lane = output feature; x row staged in LDS
__global__ __launch_bounds__(256) void k_gemm1(const float* __restrict__ x,
                                               const float* __restrict__ W1,
                                               float* __restrict__ h1, int n) {
    __shared__ float xs[4 * D_IN];
    int node0 = blockIdx.x * 4;
    int tid = threadIdx.x;
    const float2* x2 = (const float2*)(x + (size_t)node0 * D_IN);
    ((float2*)xs)[tid] = x2[tid];
    __syncthreads();
    int r = tid >> 6;
    int f = tid & 63;
    int node = node0 + r;
    if (node < n) {
        const float* xr = xs + r * D_IN;
        float acc = 0.0f;
#pragma unroll 8
        for (int k = 0; k < D_IN; ++k)
            acc = fmaf(xr[k], W1[k * D_HID + f], acc);
        h1[(size_t)node * D_HID + f] = acc;
    }
}

// ================= fused aggregation 1 + bias + ReLU + dot(W2) =================
// one wave per dst node, lane = feature; CSR gather, zero atomics.
// agg1 never materialized: epilogue computes z[i] = sum_f relu(agg+b1)*W2 in-wave.
__global__ __launch_bounds__(256) void k_gather1(const int* __restrict__ srcs,
                                                 const int* __restrict__ row_start,
                                                 const float* __restrict__ dis,
                                                 const float* __restrict__ h1,
                                                 const float* __restrict__ b1,
                                                 const float* __restrict__ W2,
                                                 float* __restrict__ z, int n) {
    int gid = blockIdx.x * 256 + threadIdx.x;
    int i = gid >> 6;
    int f = gid & 63;
    if (i >= n) return;
    float dd = dis[i];
    float acc = h1[(size_t)i * D_HID + f] * dd * dd;   // self-loop
    int beg = __builtin_amdgcn_readfirstlane(row_start[i]);
    int end = __builtin_amdgcn_readfirstlane((i < n - 1) ? row_start[i + 1] : N_EDGES);
    for (int j = beg; j < end; ++j) {
        int s = __builtin_amdgcn_readfirstlane(srcs[j]);   // wave-uniform -> scalar path
        acc = fmaf(h1[(size_t)s * D_HID + f], dis[s] * dd, acc);
    }
    float v = fmaxf(acc + b1[f], 0.0f) * W2[f];
    for (int off = 32; off > 0; off >>= 1) v += __shfl_down(v, off);
    if (f == 0) z[i] = v;
}

// ================= aggregation 2 (scalar gather) =================

__global__ void k_gather2(const int* __restrict__ srcs, const int* __restrict__ row_start,
                          const float* __restrict__ dis, const float* __restrict__ z,
                          const float* __restrict__ b2, float* __restrict__ yagg, int n) {
    int i = blockIdx.x * blockDim.x + threadIdx.x;
    if (i < n) {
        float dd = dis[i];
        float acc = z[i] * dd * dd;                       // self-loop
        int beg = row_start[i];
        int end = (i < n - 1) ? row_start[i + 1] : N_EDGES;
        for (int j = beg; j < end; ++j) {
            int s = srcs[j];
            acc = fmaf(z[s] * dis[s], dd, acc);
        }
        yagg[i] = acc + b2[0];
    }
}

// ================= output: [N,1] -> zero-padded [N,128] =================

__global__ void k_out(const float* __restrict__ yagg, float* __restrict__ out, int n) {
    int gid = blockIdx.x * blockDim.x + threadIdx.x;  // n*32 threads, each writes float4
    int i = gid >> 5;
    int t = gid & 31;
    if (i < n) {
        float4 v = make_float4(0.f, 0.f, 0.f, 0.f);
        if (t == 0) v.x = yagg[i];
        ((float4*)out)[(size_t)i * 32 + t] = v;
    }
}

extern "C" void kernel_launch(void* const* d_in, const int* in_sizes, int n_in,
                              void* d_out, int out_size, void* d_ws, size_t ws_size,
                              hipStream_t stream) {
    const float* x  = (const float*)d_in[0];
    const int*   ei = (const int*)d_in[1];   // [2, E] int32
    const float* W1 = (const float*)d_in[2];
    const float* b1 = (const float*)d_in[3];
    const float* W2 = (const float*)d_in[4];
    const float* b2 = (const float*)d_in[5];
    float* out = (float*)d_out;
    float* ws  = (float*)d_ws;

    const int n = N_NODES;
    const int E = N_EDGES;
    const int nb = (n + 255) / 256;          // scan blocks
    const int* src = ei;
    const int* dst = ei + E;

    // ws layout: floats dis[n] h1[64n] z[n] yagg[n] | ints counts[n] excl[n]
    //            row_start[n] cursor[n] bsums[1024] srcs_sorted[E]   (~35 MB)
    float* dis  = ws;
    float* h1   = dis + n;
    float* z    = h1 + (size_t)n * D_HID;
    float* yagg = z + n;
    int* counts      = (int*)(yagg + n);
    int* excl        = counts + n;
    int* row_start   = excl + n;
    int* cursor      = row_start + n;
    int* bsums       = cursor + n;
    int* srcs_sorted = bsums + 1024;

    // ---- CSR build ----
    k_zero_counts<<<nb, 256, 0, stream>>>(counts, n);
    k_count<<<(E + 255) / 256, 256, 0, stream>>>(dst, counts, E);
    k_dis<<<nb, 256, 0, stream>>>(counts, dis, n);
    k_scanA<<<nb, 256, 0, stream>>>(counts, excl, bsums, n);
    k_scanB<<<1, 64, 0, stream>>>(bsums, nb);
    k_scanC<<<nb, 256, 0, stream>>>(excl, bsums, row_start, cursor, n);
    k_fill<<<(E + 255) / 256, 256, 0, stream>>>(src, dst, cursor, srcs_sorted, E);

    // ---- layer 1 GEMM (independent of CSR build) ----
    k_gemm1<<<n / 4, 256, 0, stream>>>(x, W1, h1, n);

    // ---- fused aggregation 1 + layer-2 per-node part ----
    k_gather1<<<(n * 64) / 256, 256, 0, stream>>>(srcs_sorted, row_start, dis, h1, b1, W2, z, n);

    // ---- aggregation 2 ----
    k_gather2<<<nb, 256, 0, stream>>>(srcs_sorted, row_start, dis, z, b2, yagg, n);

    // ---- padded output ----
    k_out<<<(n * 32 + 255) / 256, 256, 0, stream>>>(yagg, out, n);
}

// Round 3
// 412.790 us; speedup vs baseline: 1.7891x; 1.3736x over previous
//
#include <hip/hip_runtime.h>

#define N_NODES 100000
#define N_EDGES 1600000
#define D_IN 128
#define D_HID 64

#define BKT_SHIFT 9
#define BKT_NODES 512                       // nodes per bucket
#define NB ((N_NODES + BKT_NODES - 1) / BKT_NODES)   // 196 buckets
#define CAP 16384                           // max edges/bucket staged in LDS (mean 8192)

// ================= bucket histogram =================

__global__ void k_init196(int* __restrict__ bucket_counts) {
    if (threadIdx.x < NB) bucket_counts[threadIdx.x] = 0;
}

__global__ __launch_bounds__(256) void k_bcount(const int* __restrict__ dst,
                                                int* __restrict__ bucket_counts, int E) {
    __shared__ int hist[NB];
    if (threadIdx.x < NB) hist[threadIdx.x] = 0;
    __syncthreads();
    int stride = gridDim.x * 256;
    for (int e = blockIdx.x * 256 + threadIdx.x; e < E; e += stride)
        atomicAdd(&hist[dst[e] >> BKT_SHIFT], 1);
    __syncthreads();
    if (threadIdx.x < NB) {
        int h = hist[threadIdx.x];
        if (h) atomicAdd(&bucket_counts[threadIdx.x], h);
    }
}

// serial scan of 196 bucket counts -> bases [NB+1], init cursors
__global__ void k_bscan(const int* __restrict__ bucket_counts,
                        int* __restrict__ bucket_base, int* __restrict__ cursor) {
    if (threadIdx.x == 0 && blockIdx.x == 0) {
        int acc = 0;
        for (int b = 0; b < NB; ++b) {
            bucket_base[b] = acc;
            cursor[b] = acc;
            acc += bucket_counts[b];
        }
        bucket_base[NB] = acc;
    }
}

// ================= partition edges into bucket regions =================
// Each block reserves space per bucket with ONE global atomic, then writes
// dense per-bucket runs -> good cache-line utilization.
__global__ __launch_bounds__(256) void k_bscatter(const int* __restrict__ src,
                                                  const int* __restrict__ dst,
                                                  int* __restrict__ cursor,
                                                  int2* __restrict__ pairs, int E) {
    __shared__ int hist[NB];
    __shared__ int lbase[NB];
    __shared__ int lcur[NB];
    int chunk = (E + gridDim.x - 1) / gridDim.x;
    int beg = blockIdx.x * chunk;
    int end = min(beg + chunk, E);
    int tid = threadIdx.x;
    if (tid < NB) hist[tid] = 0;
    __syncthreads();
    for (int e = beg + tid; e < end; e += 256)
        atomicAdd(&hist[dst[e] >> BKT_SHIFT], 1);
    __syncthreads();
    if (tid < NB) {
        int h = hist[tid];
        lbase[tid] = h ? atomicAdd(&cursor[tid], h) : 0;
        lcur[tid] = 0;
    }
    __syncthreads();
    for (int e = beg + tid; e < end; e += 256) {
        int d = dst[e];
        int bk = d >> BKT_SHIFT;
        int pos = lbase[bk] + atomicAdd(&lcur[bk], 1);
        pairs[pos] = make_int2(src[e], d);
    }
}

// ================= per-bucket counting sort (one block per bucket) =================
// Emits: srcs_sorted (coalesced), row_start, dis. Replaces count/scan/fill chain.
__global__ __launch_bounds__(256) void k_bsort(const int2* __restrict__ pairs,
                                               const int* __restrict__ bucket_base,
                                               int* __restrict__ srcs_sorted,
                                               int* __restrict__ row_start,
                                               float* __restrict__ dis, int n) {
    __shared__ int cnt[BKT_NODES];
    __shared__ int exc[BKT_NODES];
    __shared__ int sorted[CAP];
    int b = blockIdx.x;
    int base = bucket_base[b];
    int nE = bucket_base[b + 1] - base;
    int node0 = b << BKT_SHIFT;
    int tid = threadIdx.x;

    cnt[tid] = 0; cnt[tid + 256] = 0;
    __syncthreads();
    for (int k = tid; k < nE; k += 256)
        atomicAdd(&cnt[pairs[base + k].y - node0], 1);
    __syncthreads();

    // wave-0 exclusive scan of cnt[512] -> exc[512]
    if (tid < 64) {
        int lane = tid;
        int run = 0;
        for (int c = 0; c < BKT_NODES; c += 64) {
            int v = cnt[c + lane];
            int inc = v;
            for (int off = 1; off < 64; off <<= 1) {
                int t = __shfl_up(inc, off);
                if (lane >= off) inc += t;
            }
            exc[c + lane] = run + inc - v;
            run += __shfl(inc, 63);
        }
    }
    __syncthreads();

    // row_start + dis for this bucket's nodes
    for (int t = tid; t < BKT_NODES; t += 256) {
        int node = node0 + t;
        if (node < n) {
            row_start[node] = base + exc[t];
            dis[node] = rsqrtf((float)cnt[t] + 1.0f);
        }
    }
    __syncthreads();
    // turn cnt into per-node cursors
    cnt[tid] = exc[tid]; cnt[tid + 256] = exc[tid + 256];
    __syncthreads();

    if (nE <= CAP) {
        for (int k = tid; k < nE; k += 256) {
            int2 p = pairs[base + k];
            int pos = atomicAdd(&cnt[p.y - node0], 1);
            sorted[pos] = p.x;
        }
        __syncthreads();
        for (int k = tid; k < nE; k += 256)
            srcs_sorted[base + k] = sorted[k];
    } else {  // overflow fallback (statistically unreachable for uniform graphs)
        for (int k = tid; k < nE; k += 256) {
            int2 p = pairs[base + k];
            int pos = atomicAdd(&cnt[p.y - node0], 1);
            srcs_sorted[base + pos] = p.x;
        }
    }
}

// ================= layer 1 GEMM: h1 = x @ W1 =================
__global__ __launch_bounds__(256) void k_gemm1(const float* __restrict__ x,
                                               const float* __restrict__ W1,
                                               float* __restrict__ h1, int n) {
    __shared__ float xs[4 * D_IN];
    int node0 = blockIdx.x * 4;
    int tid = threadIdx.x;
    const float2* x2 = (const float2*)(x + (size_t)node0 * D_IN);
    ((float2*)xs)[tid] = x2[tid];
    __syncthreads();
    int r = tid >> 6;
    int f = tid & 63;
    int node = node0 + r;
    if (node < n) {
        const float* xr = xs + r * D_IN;
        float acc = 0.0f;
#pragma unroll 8
        for (int k = 0; k < D_IN; ++k)
            acc = fmaf(xr[k], W1[k * D_HID + f], acc);
        h1[(size_t)node * D_HID + f] = acc;
    }
}

// ================= fused aggregation 1 + bias + ReLU + dot(W2) =================
__global__ __launch_bounds__(256) void k_gather1(const int* __restrict__ srcs,
                                                 const int* __restrict__ row_start,
                                                 const float* __restrict__ dis,
                                                 const float* __restrict__ h1,
                                                 const float* __restrict__ b1,
                                                 const float* __restrict__ W2,
                                                 float* __restrict__ z, int n) {
    int gid = blockIdx.x * 256 + threadIdx.x;
    int i = gid >> 6;
    int f = gid & 63;
    if (i >= n) return;
    float dd = dis[i];
    float acc = h1[(size_t)i * D_HID + f] * dd * dd;   // self-loop
    int beg = __builtin_amdgcn_readfirstlane(row_start[i]);
    int end = __builtin_amdgcn_readfirstlane((i < n - 1) ? row_start[i + 1] : N_EDGES);
    for (int j = beg; j < end; ++j) {
        int s = __builtin_amdgcn_readfirstlane(srcs[j]);
        acc = fmaf(h1[(size_t)s * D_HID + f], dis[s] * dd, acc);
    }
    float v = fmaxf(acc + b1[f], 0.0f) * W2[f];
    for (int off = 32; off > 0; off >>= 1) v += __shfl_down(v, off);
    if (f == 0) z[i] = v;
}

// ================= aggregation 2 (scalar gather) =================
__global__ void k_gather2(const int* __restrict__ srcs, const int* __restrict__ row_start,
                          const float* __restrict__ dis, const float* __restrict__ z,
                          const float* __restrict__ b2, float* __restrict__ yagg, int n) {
    int i = blockIdx.x * blockDim.x + threadIdx.x;
    if (i < n) {
        float dd = dis[i];
        float acc = z[i] * dd * dd;
        int beg = row_start[i];
        int end = (i < n - 1) ? row_start[i + 1] : N_EDGES;
        for (int j = beg; j < end; ++j) {
            int s = srcs[j];
            acc = fmaf(z[s] * dis[s], dd, acc);
        }
        yagg[i] = acc + b2[0];
    }
}

// ================= output: [N,1] -> zero-padded [N,128] =================
__global__ void k_out(const float* __restrict__ yagg, float* __restrict__ out, int n) {
    int gid = blockIdx.x * blockDim.x + threadIdx.x;
    int i = gid >> 5;
    int t = gid & 31;
    if (i < n) {
        float4 v = make_float4(0.f, 0.f, 0.f, 0.f);
        if (t == 0) v.x = yagg[i];
        ((float4*)out)[(size_t)i * 32 + t] = v;
    }
}

extern "C" void kernel_launch(void* const* d_in, const int* in_sizes, int n_in,
                              void* d_out, int out_size, void* d_ws, size_t ws_size,
                              hipStream_t stream) {
    const float* x  = (const float*)d_in[0];
    const int*   ei = (const int*)d_in[1];   // [2, E] int32
    const float* b1 = (const float*)d_in[3];
    const float* W1 = (const float*)d_in[2];
    const float* W2 = (const float*)d_in[4];
    const float* b2 = (const float*)d_in[5];
    float* out = (float*)d_out;

    const int n = N_NODES;
    const int E = N_EDGES;
    const int* src = ei;
    const int* dst = ei + E;

    // ws layout (8B-aligned first): pairs[E] int2 | srcs_sorted[E] int |
    //   row_start[n] | bucket_counts[256] | bucket_base[260] | cursor[256] |
    //   dis[n] | h1[64n] | z[n] | yagg[n] floats      (~46.5 MB)
    int2* pairs       = (int2*)d_ws;
    int* srcs_sorted  = (int*)(pairs + N_EDGES);
    int* row_start    = srcs_sorted + N_EDGES;
    int* bucket_counts= row_start + n;
    int* bucket_base  = bucket_counts + 256;
    int* cursor       = bucket_base + 260;
    float* dis        = (float*)(cursor + 256);
    float* h1         = dis + n;
    float* z          = h1 + (size_t)n * D_HID;
    float* yagg       = z + n;

    // ---- bucketed CSR build ----
    k_init196<<<1, 256, 0, stream>>>(bucket_counts);
    k_bcount<<<256, 256, 0, stream>>>(dst, bucket_counts, E);
    k_bscan<<<1, 64, 0, stream>>>(bucket_counts, bucket_base, cursor);
    k_bscatter<<<NB, 256, 0, stream>>>(src, dst, cursor, pairs, E);
    k_bsort<<<NB, 256, 0, stream>>>(pairs, bucket_base, srcs_sorted, row_start, dis, n);

    // ---- layer 1 GEMM ----
    k_gemm1<<<n / 4, 256, 0, stream>>>(x, W1, h1, n);

    // ---- fused aggregation 1 + layer-2 per-node part ----
    k_gather1<<<(n * 64) / 256, 256, 0, stream>>>(srcs_sorted, row_start, dis, h1, b1, W2, z, n);

    // ---- aggregation 2 ----
    k_gather2<<<(n + 255) / 256, 256, 0, stream>>>(srcs_sorted, row_start, dis, z, b2, yagg, n);

    // ---- padded output ----
    k_out<<<(n * 32 + 255) / 256, 256, 0, stream>>>(yagg, out, n);
}

// Round 4
// 265.181 us; speedup vs baseline: 2.7850x; 1.5566x over previous
//
#include <hip/hip_runtime.h>

#define N_NODES 100000
#define N_EDGES 1600000
#define D_IN 128
#define D_HID 64

#define BKT_SHIFT 9
#define BKT_NODES 512
#define NB ((N_NODES + BKT_NODES - 1) / BKT_NODES)   // 196 buckets
#define BKT_CAP 10240      // >= max bucket size (binomial mean 8192, +6 sigma ~8740)

typedef __attribute__((ext_vector_type(8))) short bf16x8;
typedef __attribute__((ext_vector_type(4))) float f32x4;

__device__ __forceinline__ unsigned short f2b(float f) {
    union { float f; unsigned u; } c; c.f = f;
    unsigned r = (c.u + 0x7FFFu + ((c.u >> 16) & 1u)) >> 16;   // RNE
    return (unsigned short)r;
}
__device__ __forceinline__ float blo(unsigned u) { return __uint_as_float(u << 16); }
__device__ __forceinline__ float bhi(unsigned u) { return __uint_as_float(u & 0xffff0000u); }

// ================= bucket cursor init =================
__global__ void k_initcur(int* __restrict__ cursor) {
    int t = blockIdx.x * blockDim.x + threadIdx.x;
    if (t < NB) cursor[t] = t * BKT_CAP;
}

// ================= partition edges into fixed-capacity bucket regions =================
__global__ __launch_bounds__(256) void k_bscatter(const int* __restrict__ src,
                                                  const int* __restrict__ dst,
                                                  int* __restrict__ cursor,
                                                  int2* __restrict__ pairs, int E) {
    __shared__ int hist[NB];
    __shared__ int lbase[NB];
    __shared__ int lcur[NB];
    int chunk = (E + gridDim.x - 1) / gridDim.x;
    int beg = blockIdx.x * chunk;
    int end = min(beg + chunk, E);
    int tid = threadIdx.x;
    if (tid < NB) hist[tid] = 0;
    __syncthreads();
    for (int e = beg + tid; e < end; e += 256)
        atomicAdd(&hist[dst[e] >> BKT_SHIFT], 1);
    __syncthreads();
    if (tid < NB) {
        int h = hist[tid];
        lbase[tid] = h ? atomicAdd(&cursor[tid], h) : 0;
        lcur[tid] = 0;
    }
    __syncthreads();
    for (int e = beg + tid; e < end; e += 256) {
        int d = dst[e];
        int bk = d >> BKT_SHIFT;
        int pos = lbase[bk] + atomicAdd(&lcur[bk], 1);
        if (pos < (bk + 1) * BKT_CAP)          // capacity guard
            pairs[pos] = make_int2(src[e], d);
    }
}

// ================= per-bucket counting sort -> CSR (padded) =================
// emits srcs_sorted (bucket-padded), row_start, row_end, dis
__global__ __launch_bounds__(256) void k_bsort(const int2* __restrict__ pairs,
                                               const int* __restrict__ cursor,
                                               int* __restrict__ srcs_sorted,
                                               int* __restrict__ row_start,
                                               int* __restrict__ row_end,
                                               float* __restrict__ dis, int n) {
    __shared__ int cnt[BKT_NODES];
    __shared__ int exc[BKT_NODES];
    __shared__ int sorted[BKT_CAP];
    int b = blockIdx.x;
    int base = b * BKT_CAP;
    int nE = min(cursor[b] - base, BKT_CAP);
    int node0 = b << BKT_SHIFT;
    int tid = threadIdx.x;

    cnt[tid] = 0; cnt[tid + 256] = 0;
    __syncthreads();
    for (int k = tid; k < nE; k += 256)
        atomicAdd(&cnt[pairs[base + k].y - node0], 1);
    __syncthreads();

    if (tid < 64) {   // wave-0 exclusive scan of cnt[512]
        int lane = tid;
        int run = 0;
        for (int c = 0; c < BKT_NODES; c += 64) {
            int v = cnt[c + lane];
            int inc = v;
            for (int off = 1; off < 64; off <<= 1) {
                int t = __shfl_up(inc, off);
                if (lane >= off) inc += t;
            }
            exc[c + lane] = run + inc - v;
            run += __shfl(inc, 63);
        }
    }
    __syncthreads();

    for (int t = tid; t < BKT_NODES; t += 256) {
        int node = node0 + t;
        if (node < n) {
            int rs = base + exc[t];
            row_start[node] = rs;
            row_end[node] = rs + cnt[t];
            dis[node] = rsqrtf((float)cnt[t] + 1.0f);
        }
    }
    __syncthreads();
    cnt[tid] = exc[tid]; cnt[tid + 256] = exc[tid + 256];
    __syncthreads();

    for (int k = tid; k < nE; k += 256) {
        int2 p = pairs[base + k];
        int pos = atomicAdd(&cnt[p.y - node0], 1);
        sorted[pos] = p.x;
    }
    __syncthreads();
    for (int k = tid; k < nE; k += 256)
        srcs_sorted[base + k] = sorted[k];
}

// ================= layer 1 GEMM via bf16 MFMA: h1b = bf16(x @ W1) =================
// 64 nodes per block; x-tile + W1^T staged in LDS as bf16 (stride 136 -> 2-way/free banks)
#define LS 136
__global__ __launch_bounds__(256) void k_gemm1(const float* __restrict__ x,
                                               const float* __restrict__ W1,
                                               unsigned short* __restrict__ h1b, int n) {
    __shared__ unsigned short xs[64 * LS];   // xs[node][k]
    __shared__ unsigned short ws[64 * LS];   // ws[f][k] = W1[k][f]
    int tid = threadIdx.x;
    int node0 = blockIdx.x * 64;

    // stage W1 transposed (8192 elems)
    for (int i = 0; i < 32; ++i) {
        int e = tid + i * 256;
        int k = e >> 6, f = e & 63;
        ws[f * LS + k] = f2b(W1[e]);
    }
    // stage x tile (64 rows x 128), coalesced float4, convert to bf16
    for (int i = 0; i < 8; ++i) {
        int e4 = tid + i * 256;              // 2048 float4s
        int node = e4 >> 5;
        int k = (e4 & 31) * 4;
        float4 v = make_float4(0.f, 0.f, 0.f, 0.f);
        if (node0 + node < n)
            v = ((const float4*)x)[((size_t)(node0 + node) * D_IN + k) >> 2];
        unsigned short* p = &xs[node * LS + k];
        p[0] = f2b(v.x); p[1] = f2b(v.y); p[2] = f2b(v.z); p[3] = f2b(v.w);
    }
    __syncthreads();

    int wv = tid >> 6;
    int lane = tid & 63;
    int m16 = lane & 15;
    int q = lane >> 4;

    bf16x8 afrag[4];
#pragma unroll
    for (int ks = 0; ks < 4; ++ks)
        afrag[ks] = *(const bf16x8*)&xs[(wv * 16 + m16) * LS + ks * 32 + q * 8];

    f32x4 acc[4];
#pragma unroll
    for (int ft = 0; ft < 4; ++ft) acc[ft] = (f32x4){0.f, 0.f, 0.f, 0.f};

#pragma unroll
    for (int ft = 0; ft < 4; ++ft)
#pragma unroll
        for (int ks = 0; ks < 4; ++ks) {
            bf16x8 bfrag = *(const bf16x8*)&ws[(ft * 16 + m16) * LS + ks * 32 + q * 8];
            acc[ft] = __builtin_amdgcn_mfma_f32_16x16x32_bf16(afrag[ks], bfrag, acc[ft], 0, 0, 0);
        }

    // C layout: col(f) = lane&15, row(node) = q*4 + reg
#pragma unroll
    for (int ft = 0; ft < 4; ++ft)
#pragma unroll
        for (int r = 0; r < 4; ++r) {
            int node = node0 + wv * 16 + q * 4 + r;
            if (node < n) h1b[(size_t)node * D_HID + ft * 16 + m16] = f2b(acc[ft][r]);
        }
}

// ================= fused agg1 + bias + ReLU + dot(W2): zd = z * dis =================
// one wave per dst node; 2 edges per iteration (half-wave each, 32 lanes x bf16x2 = 128B row)
__global__ __launch_bounds__(256) void k_gather1(const int* __restrict__ srcs,
                                                 const int* __restrict__ row_start,
                                                 const int* __restrict__ row_end,
                                                 const float* __restrict__ dis,
                                                 const unsigned* __restrict__ h1u,
                                                 const float* __restrict__ b1,
                                                 const float* __restrict__ W2,
                                                 float* __restrict__ zd, int n) {
    int i = blockIdx.x * 4 + (threadIdx.x >> 6);
    if (i >= n) return;
    int lane = threadIdx.x & 63;
    int h = lane >> 5;        // half: which edge of the pair
    int f2 = lane & 31;       // feature pair index
    float dd = dis[i];

    float acc0 = 0.f, acc1 = 0.f;
    if (h == 0) {             // self-loop once
        unsigned u = h1u[(size_t)i * 32 + f2];
        float w = dd * dd;
        acc0 = w * blo(u);
        acc1 = w * bhi(u);
    }
    int beg = row_start[i], end = row_end[i];
    for (int jb = beg; jb < end; jb += 64) {
        int m = min(64, end - jb);
        int sv = (lane < m) ? srcs[jb + lane] : 0;
        float wv = (lane < m) ? dis[sv] * dd : 0.0f;
        for (int p = 0; p < m; p += 2) {
            int idx = p + h;
            int s = __shfl(sv, idx);
            float w = __shfl(wv, idx);      // 0 when idx==m (odd tail) -> safe
            unsigned u = h1u[(size_t)s * 32 + f2];
            acc0 = fmaf(w, blo(u), acc0);
            acc1 = fmaf(w, bhi(u), acc1);
        }
    }
    // combine halves (same f2 in lane and lane^32)
    acc0 += __shfl_xor(acc0, 32);
    acc1 += __shfl_xor(acc1, 32);
    float2 bb = ((const float2*)b1)[f2];
    float2 ww = ((const float2*)W2)[f2];
    float v = fmaxf(acc0 + bb.x, 0.f) * ww.x + fmaxf(acc1 + bb.y, 0.f) * ww.y;
#pragma unroll
    for (int off = 16; off > 0; off >>= 1) v += __shfl_xor(v, off);
    if (lane == 0) zd[i] = v * dd;
}

// ================= agg2: y = dd*(zd[i] + sum zd[s]) + b2 =================
__global__ void k_gather2(const int* __restrict__ srcs, const int* __restrict__ row_start,
                          const int* __restrict__ row_end, const float* __restrict__ dis,
                          const float* __restrict__ zd, const float* __restrict__ b2,
                          float* __restrict__ yagg, int n) {
    int i = blockIdx.x * blockDim.x + threadIdx.x;
    if (i < n) {
        float acc = zd[i];                    // self-loop term (zd = z*dis; *dd below)
        int beg = row_start[i], end = row_end[i];
        for (int j = beg; j < end; ++j)
            acc += zd[srcs[j]];
        yagg[i] = acc * dis[i] + b2[0];
    }
}

// ================= output: [N,1] -> zero-padded [N,128] =================
__global__ void k_out(const float* __restrict__ yagg, float* __restrict__ out, int n) {
    int gid = blockIdx.x * blockDim.x + threadIdx.x;
    int i = gid >> 5;
    int t = gid & 31;
    if (i < n) {
        float4 v = make_float4(0.f, 0.f, 0.f, 0.f);
        if (t == 0) v.x = yagg[i];
        ((float4*)out)[(size_t)i * 32 + t] = v;
    }
}

extern "C" void kernel_launch(void* const* d_in, const int* in_sizes, int n_in,
                              void* d_out, int out_size, void* d_ws, size_t ws_size,
                              hipStream_t stream) {
    const float* x  = (const float*)d_in[0];
    const int*   ei = (const int*)d_in[1];   // [2, E] int32
    const float* W1 = (const float*)d_in[2];
    const float* b1 = (const float*)d_in[3];
    const float* W2 = (const float*)d_in[4];
    const float* b2 = (const float*)d_in[5];
    float* out = (float*)d_out;

    const int n = N_NODES;
    const int E = N_EDGES;
    const int* src = ei;
    const int* dst = ei + E;

    // ws layout: pairs int2[NB*CAP] | srcs_sorted int[NB*CAP] | row_start[n] | row_end[n]
    //            | cursor[256] | dis[n] | h1b ushort[n*64] | zd[n] | yagg[n]   (~39 MB)
    int2* pairs      = (int2*)d_ws;
    int* srcs_sorted = (int*)(pairs + (size_t)NB * BKT_CAP);
    int* row_start   = srcs_sorted + (size_t)NB * BKT_CAP;
    int* row_end     = row_start + n;
    int* cursor      = row_end + n;
    float* dis       = (float*)(cursor + 256);
    unsigned short* h1b = (unsigned short*)(dis + n);
    float* zd        = (float*)(h1b + (size_t)n * D_HID);
    float* yagg      = zd + n;

    // ---- CSR build (fixed-capacity buckets; no count/scan passes) ----
    k_initcur<<<1, 256, 0, stream>>>(cursor);
    k_bscatter<<<784, 256, 0, stream>>>(src, dst, cursor, pairs, E);
    k_bsort<<<NB, 256, 0, stream>>>(pairs, cursor, srcs_sorted, row_start, row_end, dis, n);

    // ---- layer 1 GEMM (bf16 MFMA) ----
    k_gemm1<<<(n + 63) / 64, 256, 0, stream>>>(x, W1, h1b, n);

    // ---- fused aggregation 1 + layer-2 per-node part ----
    k_gather1<<<(n + 3) / 4, 256, 0, stream>>>(srcs_sorted, row_start, row_end, dis,
                                               (const unsigned*)h1b, b1, W2, zd, n);

    // ---- aggregation 2 ----
    k_gather2<<<(n + 255) / 256, 256, 0, stream>>>(srcs_sorted, row_start, row_end, dis,
                                                   zd, b2, yagg, n);

    // ---- padded output ----
    k_out<<<(n * 32 + 255) / 256, 256, 0, stream>>>(yagg, out, n);
}